// Round 1
// baseline (683.450 us; speedup 1.0000x reference)
//
#include <hip/hip_runtime.h>
#include <math.h>

// Problem constants (match reference)
constexpr int BATCH  = 65536;
constexpr int INFEAT = 2048;
constexpr int GROUP  = 256;          // rows per max-group (BLOCK in reference)
constexpr int TPB    = 1024;         // 16 waves per block
constexpr int WAVES  = TPB / 64;     // 16
constexpr int ROWS_PER_WAVE = GROUP / WAVES; // 16

// One block per 256-row group. One wave per row (64 lanes x float4 x 8 iters
// = 2048 floats). Weight vector lives in 32 VGPRs per lane, loaded once.
__global__ __launch_bounds__(TPB) void fused_gemv_gelu_max(
    const float* __restrict__ x,
    const float* __restrict__ w,
    const float* __restrict__ bias,
    float* __restrict__ out)
{
    const int grp      = blockIdx.x;          // 0..255
    const int row_base = grp * GROUP;
    const int wave     = threadIdx.x >> 6;    // 0..15
    const int lane     = threadIdx.x & 63;

    // Zero this group's 256 output slots (harness poisons d_out with 0xAA).
    if (threadIdx.x < GROUP) out[row_base + threadIdx.x] = 0.0f;

    // Weight fragment: lane i holds w[j*256 + i*4 .. +3] for j = 0..7
    float4 wr[8];
    const float4* w4 = reinterpret_cast<const float4*>(w);
    #pragma unroll
    for (int j = 0; j < 8; ++j) wr[j] = w4[j * 64 + lane];

    const float b = bias[0];
    float wmax = -INFINITY;

    // Each wave owns a contiguous 16-row chunk (128 KiB stream per wave).
    const int row0 = row_base + wave * ROWS_PER_WAVE;
    for (int r = 0; r < ROWS_PER_WAVE; ++r) {
        const float4* xp =
            reinterpret_cast<const float4*>(x + (size_t)(row0 + r) * INFEAT);
        float acc = 0.0f;
        #pragma unroll
        for (int j = 0; j < 8; ++j) {       // 8 independent 16B loads: ILP
            float4 v = xp[j * 64 + lane];
            acc = fmaf(v.x, wr[j].x, acc);
            acc = fmaf(v.y, wr[j].y, acc);
            acc = fmaf(v.z, wr[j].z, acc);
            acc = fmaf(v.w, wr[j].w, acc);
        }
        // 64-lane butterfly sum
        #pragma unroll
        for (int off = 32; off >= 1; off >>= 1)
            acc += __shfl_xor(acc, off, 64);

        // y = dot + bias; p = y/4; s = 2 * gelu_tanh(p) = p*(1+tanh(...))
        float p = (acc + b) * 0.25f;
        float t = tanhf(0.7978845608f * fmaf(0.044715f * p * p, p, p));
        float s = p * (1.0f + t);
        wmax = fmaxf(wmax, s);
    }

    // Cross-wave max via LDS, thread 0 writes the single group result.
    __shared__ float smax[WAVES];
    if (lane == 0) smax[wave] = wmax;
    __syncthreads();
    if (threadIdx.x == 0) {
        float m = smax[0];
        #pragma unroll
        for (int i = 1; i < WAVES; ++i) m = fmaxf(m, smax[i]);
        out[row_base] = m;   // ordered after the zeroing by __syncthreads
    }
}

extern "C" void kernel_launch(void* const* d_in, const int* in_sizes, int n_in,
                              void* d_out, int out_size, void* d_ws, size_t ws_size,
                              hipStream_t stream) {
    const float* x   = (const float*)d_in[0];
    const float* w   = (const float*)d_in[1];
    const float* b   = (const float*)d_in[2];
    float*       out = (float*)d_out;

    dim3 grid(BATCH / GROUP);   // 256 blocks
    dim3 block(TPB);            // 1024 threads = 16 waves
    hipLaunchKernelGGL(fused_gemv_gelu_max, grid, block, 0, stream,
                       x, w, b, out);
}